// Round 9
// baseline (213.405 us; speedup 1.0000x reference)
//
#include <hip/hip_runtime.h>
#include <math.h>

#define NBINS 182
#define NB 128   // batch

typedef unsigned short u16;
typedef __attribute__((ext_vector_type(8))) short short8;   // 8 bf16 (4 VGPRs)
typedef __attribute__((ext_vector_type(4))) float f32x4;    // MFMA accumulator

__device__ __forceinline__ u16 f2bf(float f) {
    union { float f; unsigned u; } v; v.f = f;
    unsigned r = v.u + 0x7FFF + ((v.u >> 16) & 1);   // RNE
    return (u16)(r >> 16);
}
__device__ __forceinline__ float bf2f(u16 u) {
    union { unsigned u; float f; } v; v.u = ((unsigned)u) << 16;
    return v.f;
}
__device__ __forceinline__ short8 negbf(short8 v) {
    short8 r;
#pragma unroll
    for (int i = 0; i < 8; ++i) r[i] = v[i] ^ (short)0x8000;
    return r;
}

__device__ __forceinline__ int radial_bin(int dx, int dy) {
    int d2 = dx * dx + dy * dy;
    int bin = (int)sqrtf((float)d2);
    while ((bin + 1) * (bin + 1) <= d2) ++bin;
    while (bin * bin > d2) --bin;
    return bin;
}

#define MFMA __builtin_amdgcn_mfma_f32_16x16x32_bf16

// ---------------------------------------------------------------------------
// prep (round-6 verified form, verbatim): one launch, 4 jobs by block range.
//   [0,256)      build_M row j (fp64 accum -> M fp32 + A1 bf16)
//   [256,512)    nr partial histogram -> nrpart[row][bin]
//   [512,544)    zero tbin + Tt_im row 128 (bitwise +0)
//   [544,1568)   gray grid-stride: G = luma(x) bf16
// ---------------------------------------------------------------------------
__global__ __launch_bounds__(256) void prep(const float* __restrict__ x,
                                            u16* __restrict__ G,
                                            float* __restrict__ M_re,
                                            float* __restrict__ M_im,
                                            u16* __restrict__ A1,
                                            float* __restrict__ nrpart,
                                            float* __restrict__ tbin,
                                            u16* __restrict__ Tt_im) {
    __shared__ double ctab[1024];
    __shared__ double stab[1024];
    __shared__ float s[NBINS];
    int blk = blockIdx.x;
    int t = threadIdx.x;

    if (blk < 256) {             // ---- build_M ----
        for (int i = t; i < 1024; i += 256) {
            double a = 3.14159265358979323846 * (double)i / 512.0;
            ctab[i] = cos(a);
            stab[i] = sin(a);
        }
        __syncthreads();
        int j = blk;
        int w = t;
        double re = 0.0, im = 0.0;
        int tw = 2 * w + 1;
        for (int k = 0; k < 256; ++k) {
            int e = (4 * j * k) & 1023;
            int m = (tw * k) & 1023;
            double cw = 2.0 * ctab[m];
            re += ctab[e] * cw;
            im -= stab[e] * cw;
        }
        M_re[j * 256 + w] = (float)re;
        M_im[j * 256 + w] = (float)im;
        A1[j * 256 + w] = f2bf((float)re);
        A1[(j + 256) * 256 + w] = f2bf((float)im);
    } else if (blk < 512) {      // ---- nr partial histogram, row i ----
        int i = blk - 256;
        if (t < NBINS) s[t] = 0.0f;
        __syncthreads();
        int bin = radial_bin(t - 128, i - 128);
        atomicAdd(&s[bin], 1.0f);
        __syncthreads();
        if (t < NBINS) nrpart[i * NBINS + t] = s[t];
    } else if (blk < 544) {      // ---- zero tbin + Tt_im row 128 ----
        int idx = (blk - 512) * 256 + t;
        for (int i = idx; i < NB * NBINS; i += 32 * 256) tbin[i] = 0.0f;
        for (int i = idx; i < NB * 128; i += 32 * 256) {
            int bb = i >> 7, off = (i & 127) << 1;
            *(unsigned*)(Tt_im + (size_t)bb * 65536 + 128 * 256 + off) = 0u;
        }
    } else {                     // ---- gray, grid-stride ----
        int tid = (blk - 544) * 256 + t;          // 0..262143
        for (int i = tid; i < 2097152; i += 262144) {   // 8 iters
            int idx = i * 4;
            int b = idx >> 16;
            int rem = idx & 65535;
            const float* p = x + (size_t)b * 196608 + rem;
            float4 r = *(const float4*)p;
            float4 g = *(const float4*)(p + 65536);
            float4 bl = *(const float4*)(p + 131072);
            float g0 = 0.2989f * r.x + 0.587f * g.x + 0.114f * bl.x;
            float g1 = 0.2989f * r.y + 0.587f * g.y + 0.114f * bl.y;
            float g2 = 0.2989f * r.z + 0.587f * g.z + 0.114f * bl.z;
            float g3 = 0.2989f * r.w + 0.587f * g.w + 0.114f * bl.w;
            uint2 o;
            o.x = (unsigned)f2bf(g0) | ((unsigned)f2bf(g1) << 16);
            o.y = (unsigned)f2bf(g2) | ((unsigned)f2bf(g3) << 16);
            *(uint2*)(G + idx) = o;
        }
    }
}

// ---------------------------------------------------------------------------
// Stage 1 (round-6 verified form, verbatim): Tt[r][h] = sum_w A1[r,w]*G[b,h,w]
// y=0: re rows 0..127; y=1: im rows 0..127; y=2: bit-exact row-128 replay.
// ---------------------------------------------------------------------------
__global__ __launch_bounds__(256) void s1(const u16* __restrict__ A1,
                                          const u16* __restrict__ G,
                                          u16* __restrict__ Tt_re,
                                          u16* __restrict__ Tt_im) {
    int b = blockIdx.z;
    int t = threadIdx.x;

    if (blockIdx.y == 2) {       // ---- re row 128, bit-exact MFMA replay ----
        int lane = t & 63, wv = t >> 6;
        int fr = lane & 15;
        int fk = (lane >> 4) << 3;
        const u16* Ap = A1 + (size_t)(128 + fr) * 256;   // A rows 128..143
        const u16* Gb = G + (size_t)b * 65536;
        int c0 = blockIdx.x * 128 + wv * 32;             // 2 subtiles/wave
        f32x4 acc[2];
        acc[0] = (f32x4){0.f, 0.f, 0.f, 0.f};
        acc[1] = (f32x4){0.f, 0.f, 0.f, 0.f};
        for (int kk = 0; kk < 256; kk += 32) {
            short8 af = *(const short8*)(Ap + kk + fk);
#pragma unroll
            for (int sub = 0; sub < 2; ++sub) {
                short8 bfv = *(const short8*)(Gb + (size_t)(c0 + sub * 16 + fr) * 256 + kk + fk);
                acc[sub] = MFMA(af, bfv, acc[sub], 0, 0, 0);
            }
        }
        if ((lane >> 4) == 0) {  // fragment row 0 == Tt row 128 (reg 0)
            size_t base = (size_t)b * 65536 + 128 * 256;
            Tt_re[base + c0 + lane] = f2bf(acc[0][0]);
            Tt_re[base + c0 + 16 + lane] = f2bf(acc[1][0]);
        }
        return;
    }

    __shared__ u16 As[128 * 40];   // row stride 40 (16B-aligned, conflict-free)
    __shared__ u16 Bs[128 * 40];
    int r0 = blockIdx.y * 256;    // 0: re rows 0..127 (A1 0..127), 256: im (A1 256..383)
    int h0 = blockIdx.x * 128;    // 0,128
    int lane = t & 63, wv = t >> 6;
    int wr = (wv >> 1) * 64;
    int wc = (wv & 1) * 64;
    int fr = lane & 15;
    int fk = (lane >> 4) << 3;

    f32x4 acc[4][4];
#pragma unroll
    for (int i = 0; i < 4; ++i)
#pragma unroll
        for (int j = 0; j < 4; ++j) acc[i][j] = (f32x4){0.f, 0.f, 0.f, 0.f};

    const u16* Ap = A1 + (size_t)r0 * 256;
    const u16* Gp = G + (size_t)b * 65536 + (size_t)h0 * 256;

    for (int kk = 0; kk < 256; kk += 32) {
#pragma unroll
        for (int c = t; c < 512; c += 256) {
            int row = c >> 2, off = (c & 3) << 3;
            *(uint4*)&As[row * 40 + off] =
                *(const uint4*)(Ap + (size_t)row * 256 + kk + off);
            *(uint4*)&Bs[row * 40 + off] =
                *(const uint4*)(Gp + (size_t)row * 256 + kk + off);
        }
        __syncthreads();
        short8 af[4], bfr[4];
#pragma unroll
        for (int i = 0; i < 4; ++i)
            af[i] = *(const short8*)&As[(wr + i * 16 + fr) * 40 + fk];
#pragma unroll
        for (int j = 0; j < 4; ++j)
            bfr[j] = *(const short8*)&Bs[(wc + j * 16 + fr) * 40 + fk];
#pragma unroll
        for (int i = 0; i < 4; ++i)
#pragma unroll
            for (int j = 0; j < 4; ++j)
                acc[i][j] = MFMA(af[i], bfr[j], acc[i][j], 0, 0, 0);
        __syncthreads();
    }

    u16* dst = ((r0 < 256) ? Tt_re : Tt_im) + (size_t)b * 65536;
    int rq = (lane >> 4) << 2;
#pragma unroll
    for (int i = 0; i < 4; ++i)
#pragma unroll
        for (int j = 0; j < 4; ++j) {
            int col = h0 + wc + j * 16 + fr;
#pragma unroll
            for (int reg = 0; reg < 4; ++reg) {
                int row = wr + i * 16 + rq + reg;      // 0..127
                dst[(size_t)row * 256 + col] = f2bf(acc[i][j][reg]);
            }
        }
}

// ---------------------------------------------------------------------------
// s2g (BISECT: fuse's phase-2 reorg, but B from KNOWN-GOOD global Tt):
// blocks [0,512): b=blk>>2, q=blk&3, 512 thr (8 waves); v-slice [32q,32q+32).
//   Wave wv = u-tile wv (u 0..127).  B fragments read direct from global Tt
//   rows 32q+16vt+fr (no LDS staging, no staging barriers).  Chains are
//   round-6 verbatim per accumulator:
//     r1:(ar,br)(-ai,bi)  i1:(ar,bi)(ai,br)
//     r2:(ar,br)(ai,bi)   i2:(ar,-bi)(ai,br)
//   q==0: col-128 via brf3=(fr==0 ? Tt_re row 128 : 0), bif3=0 (kept column
//   bit-identical; zero rows feed only discarded columns).
//   Epilogue: fuse's paired epilogue (one bin per pair, dx^2=v^2).
// blocks [512,640): row128, round-6 verbatim (512-thread guards added).
// ---------------------------------------------------------------------------
__global__ __launch_bounds__(512) void s2g(const u16* __restrict__ A1,
                                           const float* __restrict__ M_re,
                                           const u16* __restrict__ Tt_re,
                                           const u16* __restrict__ Tt_im,
                                           float* __restrict__ tbin) {
    __shared__ float sbins[NBINS];
    __shared__ float sM[256];
    int blk = blockIdx.x;
    int t = threadIdx.x;

    if (blk >= 512) {            // ---- row128 (round-6 verbatim) ----
        int b = blk - 512;
        if (t < 256) sM[t] = M_re[128 * 256 + t];
        __syncthreads();
        if (t > 128) return;
        const u16* pr = Tt_re + (size_t)b * 65536 + (size_t)t * 256;
        const u16* pi = Tt_im + (size_t)b * 65536 + (size_t)t * 256;
        float re = 0.0f, im = 0.0f;
        for (int h = 0; h < 256; h += 8) {
            uint4 vr = *(const uint4*)(pr + h);
            uint4 vi = *(const uint4*)(pi + h);
            unsigned wr[4] = {vr.x, vr.y, vr.z, vr.w};
            unsigned wi[4] = {vi.x, vi.y, vi.z, vi.w};
#pragma unroll
            for (int qq = 0; qq < 4; ++qq) {
                re = fmaf(sM[h + 2 * qq], bf2f((u16)(wr[qq] & 0xffff)), re);
                re = fmaf(sM[h + 2 * qq + 1], bf2f((u16)(wr[qq] >> 16)), re);
                im = fmaf(sM[h + 2 * qq], bf2f((u16)(wi[qq] & 0xffff)), im);
                im = fmaf(sM[h + 2 * qq + 1], bf2f((u16)(wi[qq] >> 16)), im);
            }
        }
        re += 1e-8f; im += 1e-8f;
        float mag = logf(sqrtf(re * re + im * im + 1e-10f) + 1e-10f);
        float wj = (t == 0 || t == 128) ? 1.0f : 2.0f;
        int dx = (t < 128) ? t : t - 256;
        int bin = radial_bin(dx, -128);
        atomicAdd(&tbin[b * NBINS + bin], wj * mag);
        return;
    }

    // ---- paired GEMM, B direct from global Tt ----
    int b = blk >> 2, q = blk & 3;
    int lane = t & 63, wv = t >> 6;     // 8 waves
    int fr = lane & 15;
    int fk = (lane >> 4) << 3;
    int rq = (lane >> 4) << 2;

    for (int i = t; i < NBINS; i += 512) sbins[i] = 0.0f;
    __syncthreads();                    // order zeroing before epilogue atomics

    const u16* Aur = A1 + (size_t)(16 * wv + fr) * 256;
    const u16* Aui = A1 + (size_t)(256 + 16 * wv + fr) * 256;
    const u16* Tr0 = Tt_re + (size_t)b * 65536 + (size_t)(32 * q + fr) * 256;
    const u16* Ti0 = Tt_im + (size_t)b * 65536 + (size_t)(32 * q + fr) * 256;
    const u16* T28 = Tt_re + (size_t)b * 65536 + (size_t)128 * 256;

    f32x4 r1[2], i1[2], r2[2], i2[2], c3r, c3i;
#pragma unroll
    for (int j = 0; j < 2; ++j) {
        r1[j] = (f32x4){0.f, 0.f, 0.f, 0.f};
        i1[j] = (f32x4){0.f, 0.f, 0.f, 0.f};
        r2[j] = (f32x4){0.f, 0.f, 0.f, 0.f};
        i2[j] = (f32x4){0.f, 0.f, 0.f, 0.f};
    }
    c3r = (f32x4){0.f, 0.f, 0.f, 0.f};
    c3i = (f32x4){0.f, 0.f, 0.f, 0.f};
    const short8 z8 = (short8){0, 0, 0, 0, 0, 0, 0, 0};

    for (int kk = 0; kk < 256; kk += 32) {
        short8 arf = *(const short8*)(Aur + kk + fk);
        short8 aif = *(const short8*)(Aui + kk + fk);
        short8 naif = negbf(aif);
        short8 brf3 = z8;
        if (q == 0 && fr == 0) brf3 = *(const short8*)(T28 + kk + fk);
#pragma unroll
        for (int vt = 0; vt < 2; ++vt) {
            short8 brf = *(const short8*)(Tr0 + (size_t)(16 * vt) * 256 + kk + fk);
            short8 bifv = *(const short8*)(Ti0 + (size_t)(16 * vt) * 256 + kk + fk);
            short8 nbif = negbf(bifv);
            r1[vt] = MFMA(arf, brf, r1[vt], 0, 0, 0);
            r1[vt] = MFMA(naif, bifv, r1[vt], 0, 0, 0);
            i1[vt] = MFMA(arf, bifv, i1[vt], 0, 0, 0);
            i1[vt] = MFMA(aif, brf, i1[vt], 0, 0, 0);
            r2[vt] = MFMA(arf, brf, r2[vt], 0, 0, 0);
            r2[vt] = MFMA(aif, bifv, r2[vt], 0, 0, 0);
            i2[vt] = MFMA(arf, nbif, i2[vt], 0, 0, 0);
            i2[vt] = MFMA(aif, brf, i2[vt], 0, 0, 0);
        }
        if (q == 0) {
            c3r = MFMA(arf, brf3, c3r, 0, 0, 0);
            c3r = MFMA(naif, z8, c3r, 0, 0, 0);
            c3i = MFMA(arf, z8, c3i, 0, 0, 0);
            c3i = MFMA(aif, brf3, c3i, 0, 0, 0);
        }
    }

    // ---- epilogue: paired columns ----
#pragma unroll
    for (int vt = 0; vt < 2; ++vt) {
        int v = 32 * q + 16 * vt + fr;        // dx = v
#pragma unroll
        for (int reg = 0; reg < 4; ++reg) {
            int u = 16 * wv + rq + reg;       // 0..127
            float wrow = (u == 0) ? 1.0f : 2.0f;
            float re1 = r1[vt][reg] + 1e-8f;
            float im1 = i1[vt][reg] + 1e-8f;
            float m1 = logf(sqrtf(re1 * re1 + im1 * im1 + 1e-10f) + 1e-10f);
            float val;
            if (v == 0) {
                val = wrow * m1;              // column 256-v doesn't exist
            } else {
                float re2 = r2[vt][reg] + 1e-8f;
                float im2 = i2[vt][reg] + 1e-8f;
                float m2 = logf(sqrtf(re2 * re2 + im2 * im2 + 1e-10f) + 1e-10f);
                val = wrow * (m1 + m2);       // same bin: dx^2 equal
            }
            atomicAdd(&sbins[radial_bin(v, u)], val);
        }
    }
    if (q == 0 && fr == 0) {                  // col-128 (kept column only)
#pragma unroll
        for (int reg = 0; reg < 4; ++reg) {
            int u = 16 * wv + rq + reg;
            float wrow = (u == 0) ? 1.0f : 2.0f;
            float re = c3r[reg] + 1e-8f;
            float im = c3i[reg] + 1e-8f;
            float mag = logf(sqrtf(re * re + im * im + 1e-10f) + 1e-10f);
            atomicAdd(&sbins[radial_bin(-128, u)], wrow * mag);
        }
    }

    __syncthreads();
    for (int i = t; i < NBINS; i += 512)
        atomicAdd(&tbin[b * NBINS + i], sbins[i]);
}

// ---------------------------------------------------------------------------
// Finalize (round-6 verbatim): nr = column-sum of nrpart; prof = tbin/nr;
// min-max over 1..179; dot bins 90..179 with w.
// ---------------------------------------------------------------------------
__global__ __launch_bounds__(192) void finalize(const float* __restrict__ tbin,
                                                const float* __restrict__ nrpart,
                                                const float* __restrict__ w,
                                                const float* __restrict__ bias,
                                                float* __restrict__ out) {
    __shared__ float prof[NBINS];
    __shared__ float smn, smx, ssum;
    int b = blockIdx.x;
    int t = threadIdx.x;
    if (t < NBINS) {
        float nr = 0.0f;
        for (int i = 0; i < 256; ++i) nr += nrpart[i * NBINS + t];
        prof[t] = tbin[b * NBINS + t] / (nr + 1e-10f);
    }
    __syncthreads();
    if (t == 0) {
        float mn = prof[1], mx = prof[1];
        for (int i = 2; i <= 179; ++i) {
            float p = prof[i];
            mn = fminf(mn, p);
            mx = fmaxf(mx, p);
        }
        smn = mn; smx = mx; ssum = 0.0f;
    }
    __syncthreads();
    if (t < 90) {
        float denom = smx - smn;
        float v = (prof[90 + t] - smn) / denom;
        if (v != v) v = 0.0f;
        atomicAdd(&ssum, v * w[t]);
    }
    __syncthreads();
    if (t == 0) out[b] = ssum + bias[0];
}

// ---------------------------------------------------------------------------
extern "C" void kernel_launch(void* const* d_in, const int* in_sizes, int n_in,
                              void* d_out, int out_size, void* d_ws, size_t ws_size,
                              hipStream_t stream) {
    const float* x = (const float*)d_in[0];     // (128,3,256,256)
    const float* w = (const float*)d_in[1];     // (1,90)
    const float* bias = (const float*)d_in[2];  // (1,)
    float* out = (float*)d_out;                 // (128,1)

    float* M_re = (float*)d_ws;                    // 65536 f
    float* M_im = M_re + 65536;                    // 65536 f
    u16* A1 = (u16*)(M_im + 65536);                // 512*256 u16
    u16* G = A1 + 131072;                          // 128*65536 u16
    u16* Tt_re = G + (size_t)NB * 65536;           // 128*65536 u16 (rows 0..128 used)
    u16* Tt_im = Tt_re + (size_t)NB * 65536;       // 128*65536 u16 (rows 0..128 used)
    float* tbin = (float*)(Tt_im + (size_t)NB * 65536);   // NB*NBINS f
    float* nrpart = tbin + NB * NBINS;             // 256*NBINS f

    prep<<<1568, 256, 0, stream>>>(x, G, M_re, M_im, A1, nrpart, tbin, Tt_im);
    s1<<<dim3(2, 3, NB), 256, 0, stream>>>(A1, G, Tt_re, Tt_im);
    s2g<<<640, 512, 0, stream>>>(A1, M_re, Tt_re, Tt_im, tbin);
    finalize<<<NB, 192, 0, stream>>>(tbin, nrpart, w, bias, out);
}